// Round 6
// baseline (756.654 us; speedup 1.0000x reference)
//
#include <hip/hip_runtime.h>
#include <hip/hip_bf16.h>

// ---------------------------------------------------------------------------
// ResidualSAGEBlock: CSR-build -> gather-mean(bf16 agg) -> MFMA bf16 dual GEMM
// (+fused BN partial stats) -> BN -> +x -> ReLU.
// N=100000, D=128, E=1600000.
// R2: CSR gather replaced float-atomic scatter: 3095->812us.
// R3: gemm LDS 48->32KB, 5 blocks/CU: 812->761us.
// R4: multi-block scan (was 230us single-CU): 761->546us.
// R5: split gather from GEMM; MFMA bf16 GEMM; fused BN stats: 546->493us.
// R6: csr_kernel had 108MB writes for 6.4MB payload (17x line amplification,
//     131us) -> two-phase binned build: append (src,dst) into 128-node
//     buckets (dense lines), then per-bucket LDS sort + coalesced copy-out.
// ---------------------------------------------------------------------------

#define D128 128
#define BSH  7          // log2(nodes per bucket)
#define BSZ  128        // nodes per bucket
#define CAP  2816       // LDS-staged csr segment capacity (mean 2048, +17sigma)

typedef short bf16x8 __attribute__((ext_vector_type(8)));
typedef float f32x4  __attribute__((ext_vector_type(4)));

static __device__ __forceinline__ unsigned short f2bf(float f) {
    unsigned u = __builtin_bit_cast(unsigned, f);
    unsigned r = u + 0x7fffu + ((u >> 16) & 1u);   // round-to-nearest-even
    return (unsigned short)(r >> 16);
}

// --- build swizzled bf16 B for MFMA ----------------------------------------
// Bsw[t][c][lane][j] = Wcat[t*32 + (lane>>4)*8 + j][c*16 + (lane&15)]
// where Wcat[k][d] = k<128 ? Wl[d][k] : Wr[d][k-128].   (4096 thr x 8 elems)
__global__ __launch_bounds__(256) void prep_kernel(
    const float* __restrict__ Wl, const float* __restrict__ Wr,
    unsigned short* __restrict__ Bsw) {
    int idx = blockIdx.x * 256 + threadIdx.x;   // 0..4095
    if (idx >= 4096) return;
    int l = idx & 63;
    int c = (idx >> 6) & 7;
    int t = idx >> 9;
    int d = c * 16 + (l & 15);
    int kbase = t * 32 + (l >> 4) * 8;
    unsigned short o[8];
#pragma unroll
    for (int j = 0; j < 8; ++j) {
        int k = kbase + j;
        float v = (k < 128) ? Wl[d * 128 + k] : Wr[d * 128 + (k - 128)];
        o[j] = f2bf(v);
    }
    *(uint4*)(Bsw + (size_t)idx * 8) = *(const uint4*)o;
}

// --- histogram of dst (4 edges/thread) -------------------------------------
__global__ __launch_bounds__(256) void hist_kernel(const int* __restrict__ dst,
                                                   int* __restrict__ deg, int E) {
    int i = (blockIdx.x * 256 + threadIdx.x) * 4;
    if (i + 3 < E) {
        int4 d4 = *(const int4*)(dst + i);
        atomicAdd(&deg[d4.x], 1);
        atomicAdd(&deg[d4.y], 1);
        atomicAdd(&deg[d4.z], 1);
        atomicAdd(&deg[d4.w], 1);
    } else {
        for (int j = i; j < E; ++j) atomicAdd(&deg[dst[j]], 1);
    }
}

// --- scan stage 1: per-block (1024 elems) sum of deg -----------------------
__global__ __launch_bounds__(256) void partial_kernel(const int* __restrict__ deg,
                                                      int* __restrict__ bsum, int N) {
    int tid  = threadIdx.x;
    int base = blockIdx.x * 1024 + tid * 4;
    int s = 0;
    if (base + 3 < N) {
        int4 v = *(const int4*)(deg + base);
        s = v.x + v.y + v.z + v.w;
    } else {
        for (int i = base; i < N; ++i) s += deg[i];
    }
    __shared__ int red[256];
    red[tid] = s;
    __syncthreads();
    for (int off = 128; off > 0; off >>= 1) {
        if (tid < off) red[tid] += red[tid + off];
        __syncthreads();
    }
    if (tid == 0) bsum[blockIdx.x] = red[0];
}

// --- scan stage 2: exclusive scan of block sums (NB <= 1024); offs[N]=E ----
__global__ __launch_bounds__(1024) void scan_bsum_kernel(
    const int* __restrict__ bsum, int* __restrict__ ebsum,
    int NB, int* __restrict__ offsN, int E) {
    __shared__ int buf[2][1024];
    int t = threadIdx.x;
    int v = (t < NB) ? bsum[t] : 0;
    buf[0][t] = v;
    __syncthreads();
    int pi = 0;
    for (int off = 1; off < 1024; off <<= 1) {
        int u = buf[pi][t];
        if (t >= off) u += buf[pi][t - off];
        buf[pi ^ 1][t] = u;
        __syncthreads();
        pi ^= 1;
    }
    if (t < NB) ebsum[t] = buf[pi][t] - v;   // exclusive prefix
    if (t == 0) *offsN = E;
}

// --- scan stage 3: per-block exclusive scan + ebsum offset -----------------
__global__ __launch_bounds__(256) void scan_final_kernel(
    const int* __restrict__ deg, const int* __restrict__ ebsum,
    int* __restrict__ offs, int N) {
    int tid  = threadIdx.x;
    int base = blockIdx.x * 1024 + tid * 4;
    int d0 = 0, d1 = 0, d2 = 0, d3 = 0;
    if (base + 3 < N) {
        int4 v = *(const int4*)(deg + base);
        d0 = v.x; d1 = v.y; d2 = v.z; d3 = v.w;
    } else {
        if (base     < N) d0 = deg[base];
        if (base + 1 < N) d1 = deg[base + 1];
        if (base + 2 < N) d2 = deg[base + 2];
        if (base + 3 < N) d3 = deg[base + 3];
    }
    int s = d0 + d1 + d2 + d3;
    __shared__ int buf[2][256];
    buf[0][tid] = s;
    __syncthreads();
    int pi = 0;
    for (int off = 1; off < 256; off <<= 1) {
        int u = buf[pi][tid];
        if (tid >= off) u += buf[pi][tid - off];
        buf[pi ^ 1][tid] = u;
        __syncthreads();
        pi ^= 1;
    }
    int pre = buf[pi][tid] - s + ebsum[blockIdx.x];
    if (base + 3 < N) {
        int4 o = make_int4(pre, pre + d0, pre + d0 + d1, pre + d0 + d1 + d2);
        *(int4*)(offs + base) = o;
    } else {
        int p = pre;
        if (base     < N) { offs[base]     = p; p += d0; }
        if (base + 1 < N) { offs[base + 1] = p; p += d1; }
        if (base + 2 < N) { offs[base + 2] = p; p += d2; }
        if (base + 3 < N) { offs[base + 3] = p; }
    }
}

// --- bucket cursor init: bcur[b] = offs[b*BSZ] -----------------------------
__global__ __launch_bounds__(256) void bcurinit_kernel(const int* __restrict__ offs,
                                                       int* __restrict__ bcur, int NBUK) {
    int b = blockIdx.x * 256 + threadIdx.x;
    if (b < NBUK) bcur[b] = offs[(size_t)b << BSH];
}

// --- phase A: bin edges into 128-node dst buckets (dense appended writes) --
__global__ __launch_bounds__(256) void bin_kernel(
    const int* __restrict__ src, const int* __restrict__ dst,
    int* __restrict__ bcur, int2* __restrict__ pairs, int E) {
    int i = (blockIdx.x * 256 + threadIdx.x) * 4;
    if (i + 3 < E) {
        int4 d4 = *(const int4*)(dst + i);
        int4 s4 = *(const int4*)(src + i);
        int p;
        p = atomicAdd(&bcur[d4.x >> BSH], 1); pairs[p] = make_int2(s4.x, d4.x);
        p = atomicAdd(&bcur[d4.y >> BSH], 1); pairs[p] = make_int2(s4.y, d4.y);
        p = atomicAdd(&bcur[d4.z >> BSH], 1); pairs[p] = make_int2(s4.z, d4.z);
        p = atomicAdd(&bcur[d4.w >> BSH], 1); pairs[p] = make_int2(s4.w, d4.w);
    } else {
        for (int j = i; j < E; ++j) {
            int d = dst[j];
            int p = atomicAdd(&bcur[d >> BSH], 1);
            pairs[p] = make_int2(src[j], d);
        }
    }
}

// --- phase B: per-bucket LDS counting-sort into csr, coalesced copy-out ----
__global__ __launch_bounds__(256) void csrbuild_kernel(
    const int2* __restrict__ pairs, const int* __restrict__ offs,
    int* __restrict__ csr, int N) {
    __shared__ int lcur[BSZ];
    __shared__ int lcsr[CAP];
    int b   = blockIdx.x;
    int tid = threadIdx.x;
    int nlo = b << BSH;
    int nhi = min(nlo + BSZ, N);
    int base = offs[nlo];
    int end  = offs[nhi];          // offs[N] == E for the last bucket
    int len  = end - base;
    if (tid < BSZ) {
        int n = nlo + tid;
        lcur[tid] = ((n < nhi) ? offs[n] : end) - base;
    }
    __syncthreads();
    if (len <= CAP) {
        for (int i = tid; i < len; i += 256) {
            int2 p = pairs[base + i];
            int pos = atomicAdd(&lcur[p.y - nlo], 1);
            lcsr[pos] = p.x;
        }
        __syncthreads();
        for (int i = tid; i < len; i += 256) csr[base + i] = lcsr[i];
    } else {
        // overflow fallback (should not trigger for this input)
        for (int i = tid; i < len; i += 256) {
            int2 p = pairs[base + i];
            int pos = atomicAdd(&lcur[p.y - nlo], 1);
            csr[base + pos] = p.x;
        }
    }
}

// --- standalone gather-mean: agg_bf16[n][:] = mean of x[src] rows ----------
// 8 nodes/block (32 lanes each, 4 features/lane). No LDS -> full occupancy.
__global__ __launch_bounds__(256) void gather_kernel(
    const int* __restrict__ offs, const int* __restrict__ csr,
    const float* __restrict__ x, unsigned short* __restrict__ aggb,
    int N, int Npad) {
    int tid  = threadIdx.x;
    int lane = tid & 31;
    int n    = blockIdx.x * 8 + (tid >> 5);
    if (n >= Npad) return;
    float4 a0 = make_float4(0.f, 0.f, 0.f, 0.f);
    float4 a1 = a0, a2 = a0, a3 = a0;
    float inv = 0.f;
    if (n < N) {
        int beg = offs[n], end = offs[n + 1];
        int k = beg;
        for (; k + 3 < end; k += 4) {
            int s0 = csr[k], s1 = csr[k + 1], s2 = csr[k + 2], s3 = csr[k + 3];
            float4 v0 = ((const float4*)(x + (size_t)s0 * D128))[lane];
            float4 v1 = ((const float4*)(x + (size_t)s1 * D128))[lane];
            float4 v2 = ((const float4*)(x + (size_t)s2 * D128))[lane];
            float4 v3 = ((const float4*)(x + (size_t)s3 * D128))[lane];
            a0.x += v0.x; a0.y += v0.y; a0.z += v0.z; a0.w += v0.w;
            a1.x += v1.x; a1.y += v1.y; a1.z += v1.z; a1.w += v1.w;
            a2.x += v2.x; a2.y += v2.y; a2.z += v2.z; a2.w += v2.w;
            a3.x += v3.x; a3.y += v3.y; a3.z += v3.z; a3.w += v3.w;
        }
        for (; k < end; ++k) {
            int s0 = csr[k];
            float4 v0 = ((const float4*)(x + (size_t)s0 * D128))[lane];
            a0.x += v0.x; a0.y += v0.y; a0.z += v0.z; a0.w += v0.w;
        }
        if (end > beg) inv = 1.0f / (float)(end - beg);
    }
    float f0 = ((a0.x + a1.x) + (a2.x + a3.x)) * inv;
    float f1 = ((a0.y + a1.y) + (a2.y + a3.y)) * inv;
    float f2 = ((a0.z + a1.z) + (a2.z + a3.z)) * inv;
    float f3 = ((a0.w + a1.w) + (a2.w + a3.w)) * inv;
    unsigned short o[4] = {f2bf(f0), f2bf(f1), f2bf(f2), f2bf(f3)};
    *(uint2*)(aggb + (size_t)n * D128 + lane * 4) = *(const uint2*)o;
}

// --- MFMA dual GEMM + fused BN partial stats -------------------------------
// Block = 256 thr = 4 waves; wave w owns 32 rows (2 x 16-row A-frags);
// 8 col-tiles of 16 -> full D=128. K=256: ksteps 0-3 read agg_bf16,
// 4-7 read x (fp32 -> bf16 in-flight). Per-wave column sums -> pstat.
__global__ __launch_bounds__(256) void mfma_kernel(
    const unsigned short* __restrict__ aggb, const float* __restrict__ x,
    const unsigned short* __restrict__ Bsw, const float* __restrict__ bl,
    float* __restrict__ h, float* __restrict__ pstat, int N) {
    int tid  = threadIdx.x;
    int w    = tid >> 6;
    int lane = tid & 63;
    int lc   = lane & 15;    // tile col
    int lq   = lane >> 4;    // quarter
    int rowBase = blockIdx.x * 128 + w * 32;

    f32x4 acc[2][8];
#pragma unroll
    for (int c = 0; c < 8; ++c) {
        float b = bl[c * 16 + lc];
        f32x4 v = {b, b, b, b};
        acc[0][c] = v;
        acc[1][c] = v;
    }

    int r0  = rowBase + lc;         // A-frag rows (m = lane&15)
    int r1  = rowBase + 16 + lc;
    int r0c = min(r0, N - 1);       // clamp for x reads (x has exactly N rows)
    int r1c = min(r1, N - 1);

    for (int t = 0; t < 8; ++t) {
        bf16x8 a0, a1;
        if (t < 4) {
            int off = t * 32 + lq * 8;
            a0 = *(const bf16x8*)(aggb + (size_t)r0 * D128 + off);
            a1 = *(const bf16x8*)(aggb + (size_t)r1 * D128 + off);
        } else {
            int off = (t - 4) * 32 + lq * 8;
            const float* p0 = x + (size_t)r0c * D128 + off;
            const float* p1 = x + (size_t)r1c * D128 + off;
            float4 u0 = *(const float4*)p0, u1 = *(const float4*)(p0 + 4);
            float4 v0 = *(const float4*)p1, v1 = *(const float4*)(p1 + 4);
            float tu[8] = {u0.x, u0.y, u0.z, u0.w, u1.x, u1.y, u1.z, u1.w};
            float tv[8] = {v0.x, v0.y, v0.z, v0.w, v1.x, v1.y, v1.z, v1.w};
#pragma unroll
            for (int j = 0; j < 8; ++j) {
                a0[j] = (short)f2bf(tu[j]);
                a1[j] = (short)f2bf(tv[j]);
            }
        }
#pragma unroll
        for (int c = 0; c < 8; ++c) {
            bf16x8 bf = *(const bf16x8*)(Bsw + ((size_t)((t * 8 + c) * 64 + lane)) * 8);
            acc[0][c] = __builtin_amdgcn_mfma_f32_16x16x32_bf16(a0, bf, acc[0][c], 0, 0, 0);
            acc[1][c] = __builtin_amdgcn_mfma_f32_16x16x32_bf16(a1, bf, acc[1][c], 0, 0, 0);
        }
    }

    // epilogue: store h + per-wave column partial stats
    float s[8], ss[8];
#pragma unroll
    for (int c = 0; c < 8; ++c) { s[c] = 0.f; ss[c] = 0.f; }
#pragma unroll
    for (int rh = 0; rh < 2; ++rh) {
#pragma unroll
        for (int reg = 0; reg < 4; ++reg) {
            int row = rowBase + rh * 16 + lq * 4 + reg;   // C-layout row
            if (row < N) {
#pragma unroll
                for (int c = 0; c < 8; ++c) {
                    float v = acc[rh][c][reg];
                    h[(size_t)row * D128 + c * 16 + lc] = v;
                    s[c]  += v;
                    ss[c] += v * v;
                }
            }
        }
    }
#pragma unroll
    for (int c = 0; c < 8; ++c) {
        s[c]  += __shfl_xor(s[c], 16, 64);
        s[c]  += __shfl_xor(s[c], 32, 64);
        ss[c] += __shfl_xor(ss[c], 16, 64);
        ss[c] += __shfl_xor(ss[c], 32, 64);
    }
    if (lq == 0) {
        size_t prow = ((size_t)blockIdx.x * 4 + w) * 256;
#pragma unroll
        for (int c = 0; c < 8; ++c) {
            pstat[prow + c * 16 + lc]       = s[c];
            pstat[prow + 128 + c * 16 + lc] = ss[c];
        }
    }
}

// --- reduce per-wave partial stats -> stats[256] ---------------------------
__global__ __launch_bounds__(256) void statreduce_kernel(
    const float* __restrict__ pstat, float* __restrict__ stats, int NP) {
    int tid = threadIdx.x;
    float loc = 0.f;
    for (int r = blockIdx.x; r < NP; r += gridDim.x)
        loc += pstat[(size_t)r * 256 + tid];
    atomicAdd(&stats[tid], loc);
}

// --- BN params: scale/shift per feature ------------------------------------
__global__ void bnparam_kernel(const float* __restrict__ stats,
                               const float* __restrict__ gamma,
                               const float* __restrict__ beta,
                               float* __restrict__ scl, float* __restrict__ shf,
                               float invN) {
    int d = threadIdx.x;
    float mean = stats[d] * invN;
    float var  = stats[D128 + d] * invN - mean * mean;
    float istd = rsqrtf(var + 1e-5f);
    float sc   = gamma[d] * istd;
    scl[d] = sc;
    shf[d] = beta[d] - mean * sc;
}

// --- finalize: out = relu(h*scale + shift + x), float4, in-place on d_out --
__global__ __launch_bounds__(256) void finalize_kernel(
    const float* __restrict__ h, const float* __restrict__ x,
    const float* __restrict__ scl, const float* __restrict__ shf,
    float* __restrict__ out, long long total4) {
    long long i = (long long)blockIdx.x * 256 + threadIdx.x;
    if (i >= total4) return;
    int d = (int)((i * 4) & 127);
    float4 hv = ((const float4*)h)[i];
    float4 xv = ((const float4*)x)[i];
    float4 sc = *(const float4*)(scl + d);
    float4 sh = *(const float4*)(shf + d);
    float4 o;
    o.x = fmaxf(fmaf(hv.x, sc.x, sh.x) + xv.x, 0.f);
    o.y = fmaxf(fmaf(hv.y, sc.y, sh.y) + xv.y, 0.f);
    o.z = fmaxf(fmaf(hv.z, sc.z, sh.z) + xv.z, 0.f);
    o.w = fmaxf(fmaf(hv.w, sc.w, sh.w) + xv.w, 0.f);
    ((float4*)out)[i] = o;
}

extern "C" void kernel_launch(void* const* d_in, const int* in_sizes, int n_in,
                              void* d_out, int out_size, void* d_ws, size_t ws_size,
                              hipStream_t stream) {
    const float* x     = (const float*)d_in[0];
    const int*   eidx  = (const int*)d_in[1];
    const float* W_l   = (const float*)d_in[2];
    const float* b_l   = (const float*)d_in[3];
    const float* W_r   = (const float*)d_in[4];
    const float* gamma = (const float*)d_in[5];
    const float* beta  = (const float*)d_in[6];

    const int D = in_sizes[3];            // 128
    const int N = in_sizes[0] / D;        // 100000
    const int E = in_sizes[1] / 2;        // 1600000

    const int* src = eidx;
    const int* dst = eidx + E;

    const int NB    = (N + 1023) / 1024;      // scan blocks
    const int NBLK  = (N + 127) / 128;        // mfma blocks (782)
    const int Npad  = NBLK * 128;             // padded rows (100096)
    const int NP    = NBLK * 4;               // pstat rows
    const int NBUK  = (N + BSZ - 1) / BSZ;    // csr buckets (782)

    // workspace layout (byte cursor, 64B-aligned chunks)
    char* wp = (char*)d_ws;
    auto alloc = [&](size_t bytes) {
        char* p = wp;
        wp += (bytes + 63) & ~(size_t)63;
        return p;
    };
    int*   deg    = (int*)  alloc((size_t)N * 4 + 256 * 4);   // deg + stats (contig, zeroed)
    float* stats  = (float*)(deg + N);
    int*   offs   = (int*)  alloc((size_t)(N + 1) * 4);
    int*   csr    = (int*)  alloc((size_t)E * 4);             // reused as pstat by mfma
    int2*  pairs  = (int2*) alloc((size_t)E * 8);
    int*   bsum   = (int*)  alloc((size_t)NB * 4);
    int*   ebsum  = (int*)  alloc((size_t)NB * 4);
    int*   bcur   = (int*)  alloc((size_t)NBUK * 4);
    float* scl    = (float*)alloc(128 * 4);
    float* shf    = (float*)alloc(128 * 4);
    unsigned short* Bsw  = (unsigned short*)alloc(4096 * 16); // 8*8*64 frags x 16B
    unsigned short* aggb = (unsigned short*)alloc((size_t)Npad * D128 * 2);
    float* pstat = (float*)csr;                               // mfma runs after gather

    float* h = (float*)d_out;                                 // h lives in d_out

    // zero deg + stats
    hipMemsetAsync(deg, 0, (size_t)(N + 256) * sizeof(int), stream);

    prep_kernel<<<16, 256, 0, stream>>>(W_l, W_r, Bsw);

    hist_kernel<<<(E / 4 + 255) / 256 + 1, 256, 0, stream>>>(dst, deg, E);

    partial_kernel<<<NB, 256, 0, stream>>>(deg, bsum, N);
    scan_bsum_kernel<<<1, 1024, 0, stream>>>(bsum, ebsum, NB, offs + N, E);
    scan_final_kernel<<<NB, 256, 0, stream>>>(deg, ebsum, offs, N);

    bcurinit_kernel<<<(NBUK + 255) / 256, 256, 0, stream>>>(offs, bcur, NBUK);

    bin_kernel<<<(E / 4 + 255) / 256 + 1, 256, 0, stream>>>(src, dst, bcur, pairs, E);

    csrbuild_kernel<<<NBUK, 256, 0, stream>>>(pairs, offs, csr, N);

    gather_kernel<<<Npad / 8, 256, 0, stream>>>(offs, csr, x, aggb, N, Npad);

    mfma_kernel<<<NBLK, 256, 0, stream>>>(aggb, x, Bsw, b_l, h, pstat, N);

    statreduce_kernel<<<64, 256, 0, stream>>>(pstat, stats, NP);

    bnparam_kernel<<<1, 128, 0, stream>>>(stats, gamma, beta, scl, shf, 1.0f / (float)N);

    {
        long long total4 = (long long)N * D128 / 4;
        finalize_kernel<<<(int)((total4 + 255) / 256), 256, 0, stream>>>(
            h, x, scl, shf, (float*)d_out, total4);
    }
}

// Round 7
// 408.645 us; speedup vs baseline: 1.8516x; 1.8516x over previous
//
#include <hip/hip_runtime.h>
#include <hip/hip_bf16.h>

// ---------------------------------------------------------------------------
// ResidualSAGEBlock: block-private bucket sort -> CSR -> gather-mean(bf16) ->
// MFMA bf16 dual GEMM (+fused BN stats) -> BN -> +x -> ReLU.
// N=100000, D=128, E=1600000.
// R2: CSR gather replaced float-atomic scatter: 3095->812us.
// R3: gemm LDS 48->32KB, 5 blocks/CU: 812->761us.
// R4: multi-block scan (was 230us single-CU): 761->546us.
// R5: split gather from GEMM; MFMA bf16 GEMM; fused BN stats: 546->493us.
// R6 FAILED: global-atomic bucket append still amplified (80MB writes, lines
//     shared across XCDs) + 2048-deep atomic serialization: 493->757us.
// R7: 3-pass block-PRIVATE counting sort: per-block LDS bucket hist -> scan
//     (bucket-major, block-minor) -> scatter into block-private ranges. No
//     global atomics, every pairs line written by exactly one block.
// ---------------------------------------------------------------------------

#define D128 128
#define BSH2 8          // log2(nodes per bucket)
#define BSZ2 256        // nodes per bucket
#define MAXBUK 1024     // LDS array bound for buckets (NBUK=391 actual)
#define SBLK 256        // sort blocks
#define CAP  5120       // csrbuild LDS capacity (mean 4096, +16 sigma)

typedef short bf16x8 __attribute__((ext_vector_type(8)));
typedef float f32x4  __attribute__((ext_vector_type(4)));

static __device__ __forceinline__ unsigned short f2bf(float f) {
    unsigned u = __builtin_bit_cast(unsigned, f);
    unsigned r = u + 0x7fffu + ((u >> 16) & 1u);   // round-to-nearest-even
    return (unsigned short)(r >> 16);
}

// --- build swizzled bf16 B for MFMA ----------------------------------------
__global__ __launch_bounds__(256) void prep_kernel(
    const float* __restrict__ Wl, const float* __restrict__ Wr,
    unsigned short* __restrict__ Bsw) {
    int idx = blockIdx.x * 256 + threadIdx.x;   // 0..4095
    if (idx >= 4096) return;
    int l = idx & 63;
    int c = (idx >> 6) & 7;
    int t = idx >> 9;
    int d = c * 16 + (l & 15);
    int kbase = t * 32 + (l >> 4) * 8;
    unsigned short o[8];
#pragma unroll
    for (int j = 0; j < 8; ++j) {
        int k = kbase + j;
        float v = (k < 128) ? Wl[d * 128 + k] : Wr[d * 128 + (k - 128)];
        o[j] = f2bf(v);
    }
    *(uint4*)(Bsw + (size_t)idx * 8) = *(const uint4*)o;
}

// --- histogram of dst (node-level deg, 4 edges/thread) ---------------------
__global__ __launch_bounds__(256) void hist_kernel(const int* __restrict__ dst,
                                                   int* __restrict__ deg, int E) {
    int i = (blockIdx.x * 256 + threadIdx.x) * 4;
    if (i + 3 < E) {
        int4 d4 = *(const int4*)(dst + i);
        atomicAdd(&deg[d4.x], 1);
        atomicAdd(&deg[d4.y], 1);
        atomicAdd(&deg[d4.z], 1);
        atomicAdd(&deg[d4.w], 1);
    } else {
        for (int j = i; j < E; ++j) atomicAdd(&deg[dst[j]], 1);
    }
}

// --- scan stage 1: per-block (1024 elems) partial sums ---------------------
__global__ __launch_bounds__(256) void partial_kernel(const int* __restrict__ deg,
                                                      int* __restrict__ bsum, int N) {
    int tid  = threadIdx.x;
    int base = blockIdx.x * 1024 + tid * 4;
    int s = 0;
    if (base + 3 < N) {
        int4 v = *(const int4*)(deg + base);
        s = v.x + v.y + v.z + v.w;
    } else {
        for (int i = base; i < N; ++i) s += deg[i];
    }
    __shared__ int red[256];
    red[tid] = s;
    __syncthreads();
    for (int off = 128; off > 0; off >>= 1) {
        if (tid < off) red[tid] += red[tid + off];
        __syncthreads();
    }
    if (tid == 0) bsum[blockIdx.x] = red[0];
}

// --- scan stage 2: exclusive scan of block sums (NB <= 1024); out[N]=E -----
__global__ __launch_bounds__(1024) void scan_bsum_kernel(
    const int* __restrict__ bsum, int* __restrict__ ebsum,
    int NB, int* __restrict__ offsN, int E) {
    __shared__ int buf[2][1024];
    int t = threadIdx.x;
    int v = (t < NB) ? bsum[t] : 0;
    buf[0][t] = v;
    __syncthreads();
    int pi = 0;
    for (int off = 1; off < 1024; off <<= 1) {
        int u = buf[pi][t];
        if (t >= off) u += buf[pi][t - off];
        buf[pi ^ 1][t] = u;
        __syncthreads();
        pi ^= 1;
    }
    if (t < NB) ebsum[t] = buf[pi][t] - v;   // exclusive prefix
    if (t == 0) *offsN = E;
}

// --- scan stage 3: per-block exclusive scan + ebsum offset -----------------
__global__ __launch_bounds__(256) void scan_final_kernel(
    const int* __restrict__ deg, const int* __restrict__ ebsum,
    int* __restrict__ offs, int N) {
    int tid  = threadIdx.x;
    int base = blockIdx.x * 1024 + tid * 4;
    int d0 = 0, d1 = 0, d2 = 0, d3 = 0;
    if (base + 3 < N) {
        int4 v = *(const int4*)(deg + base);
        d0 = v.x; d1 = v.y; d2 = v.z; d3 = v.w;
    } else {
        if (base     < N) d0 = deg[base];
        if (base + 1 < N) d1 = deg[base + 1];
        if (base + 2 < N) d2 = deg[base + 2];
        if (base + 3 < N) d3 = deg[base + 3];
    }
    int s = d0 + d1 + d2 + d3;
    __shared__ int buf[2][256];
    buf[0][tid] = s;
    __syncthreads();
    int pi = 0;
    for (int off = 1; off < 256; off <<= 1) {
        int u = buf[pi][tid];
        if (tid >= off) u += buf[pi][tid - off];
        buf[pi ^ 1][tid] = u;
        __syncthreads();
        pi ^= 1;
    }
    int pre = buf[pi][tid] - s + ebsum[blockIdx.x];
    if (base + 3 < N) {
        int4 o = make_int4(pre, pre + d0, pre + d0 + d1, pre + d0 + d1 + d2);
        *(int4*)(offs + base) = o;
    } else {
        int p = pre;
        if (base     < N) { offs[base]     = p; p += d0; }
        if (base + 1 < N) { offs[base + 1] = p; p += d1; }
        if (base + 2 < N) { offs[base + 2] = p; p += d2; }
        if (base + 3 < N) { offs[base + 3] = p; }
    }
}

// --- sort pass 1: per-block bucket histogram -------------------------------
// Block b scans its edge chunk; LDS hist over NBUK buckets; writes
// ghist[k*SBLK + b] (bucket-major for the linear scan).
__global__ __launch_bounds__(256) void bhist_kernel(
    const int* __restrict__ dst, int* __restrict__ ghist,
    int E, int chunk, int NBUK) {
    __shared__ int lh[MAXBUK];
    int tid = threadIdx.x;
    int b   = blockIdx.x;
    for (int i = tid; i < NBUK; i += 256) lh[i] = 0;
    __syncthreads();
    int beg = b * chunk;
    int end = min(beg + chunk, E);
    for (int i = beg + tid; i < end; i += 256)
        atomicAdd(&lh[dst[i] >> BSH2], 1);
    __syncthreads();
    for (int i = tid; i < NBUK; i += 256) ghist[i * SBLK + b] = lh[i];
}

// --- sort pass 2: scatter edges into block-private (bucket,block) ranges ---
__global__ __launch_bounds__(256) void bscatter_kernel(
    const int* __restrict__ src, const int* __restrict__ dst,
    const int* __restrict__ gsc, int2* __restrict__ pairs,
    int E, int chunk, int NBUK) {
    __shared__ int lcur[MAXBUK];
    int tid = threadIdx.x;
    int b   = blockIdx.x;
    for (int i = tid; i < NBUK; i += 256) lcur[i] = gsc[i * SBLK + b];
    __syncthreads();
    int beg = b * chunk;
    int end = min(beg + chunk, E);
    for (int i = beg + tid; i < end; i += 256) {
        int d = dst[i];
        int s = src[i];
        int pos = atomicAdd(&lcur[d >> BSH2], 1);
        pairs[pos] = make_int2(s, d);
    }
}

// --- per-bucket LDS counting-sort into csr, coalesced copy-out -------------
__global__ __launch_bounds__(256) void csrbuild_kernel(
    const int2* __restrict__ pairs, const int* __restrict__ offs,
    int* __restrict__ csr, int N) {
    __shared__ int lcur[BSZ2];
    __shared__ int lcsr[CAP];
    int b   = blockIdx.x;
    int tid = threadIdx.x;
    int nlo = b << BSH2;
    int nhi = min(nlo + BSZ2, N);
    int base = offs[nlo];
    int end  = offs[nhi];          // offs[N] == E for the last bucket
    int len  = end - base;
    if (tid < BSZ2) {
        int n = nlo + tid;
        lcur[tid] = ((n < nhi) ? offs[n] : end) - base;
    }
    __syncthreads();
    if (len <= CAP) {
        for (int i = tid; i < len; i += 256) {
            int2 p = pairs[base + i];
            int pos = atomicAdd(&lcur[p.y - nlo], 1);
            lcsr[pos] = p.x;
        }
        __syncthreads();
        for (int i = tid; i < len; i += 256) csr[base + i] = lcsr[i];
    } else {
        // overflow fallback (statistically unreachable for this input)
        for (int i = tid; i < len; i += 256) {
            int2 p = pairs[base + i];
            int pos = atomicAdd(&lcur[p.y - nlo], 1);
            csr[base + pos] = p.x;
        }
    }
}

// --- standalone gather-mean: agg_bf16[n][:] = mean of x[src] rows ----------
__global__ __launch_bounds__(256) void gather_kernel(
    const int* __restrict__ offs, const int* __restrict__ csr,
    const float* __restrict__ x, unsigned short* __restrict__ aggb,
    int N, int Npad) {
    int tid  = threadIdx.x;
    int lane = tid & 31;
    int n    = blockIdx.x * 8 + (tid >> 5);
    if (n >= Npad) return;
    float4 a0 = make_float4(0.f, 0.f, 0.f, 0.f);
    float4 a1 = a0, a2 = a0, a3 = a0;
    float inv = 0.f;
    if (n < N) {
        int beg = offs[n], end = offs[n + 1];
        int k = beg;
        for (; k + 3 < end; k += 4) {
            int s0 = csr[k], s1 = csr[k + 1], s2 = csr[k + 2], s3 = csr[k + 3];
            float4 v0 = ((const float4*)(x + (size_t)s0 * D128))[lane];
            float4 v1 = ((const float4*)(x + (size_t)s1 * D128))[lane];
            float4 v2 = ((const float4*)(x + (size_t)s2 * D128))[lane];
            float4 v3 = ((const float4*)(x + (size_t)s3 * D128))[lane];
            a0.x += v0.x; a0.y += v0.y; a0.z += v0.z; a0.w += v0.w;
            a1.x += v1.x; a1.y += v1.y; a1.z += v1.z; a1.w += v1.w;
            a2.x += v2.x; a2.y += v2.y; a2.z += v2.z; a2.w += v2.w;
            a3.x += v3.x; a3.y += v3.y; a3.z += v3.z; a3.w += v3.w;
        }
        for (; k < end; ++k) {
            int s0 = csr[k];
            float4 v0 = ((const float4*)(x + (size_t)s0 * D128))[lane];
            a0.x += v0.x; a0.y += v0.y; a0.z += v0.z; a0.w += v0.w;
        }
        if (end > beg) inv = 1.0f / (float)(end - beg);
    }
    float f0 = ((a0.x + a1.x) + (a2.x + a3.x)) * inv;
    float f1 = ((a0.y + a1.y) + (a2.y + a3.y)) * inv;
    float f2 = ((a0.z + a1.z) + (a2.z + a3.z)) * inv;
    float f3 = ((a0.w + a1.w) + (a2.w + a3.w)) * inv;
    unsigned short o[4] = {f2bf(f0), f2bf(f1), f2bf(f2), f2bf(f3)};
    *(uint2*)(aggb + (size_t)n * D128 + lane * 4) = *(const uint2*)o;
}

// --- MFMA dual GEMM + fused BN partial stats -------------------------------
__global__ __launch_bounds__(256) void mfma_kernel(
    const unsigned short* __restrict__ aggb, const float* __restrict__ x,
    const unsigned short* __restrict__ Bsw, const float* __restrict__ bl,
    float* __restrict__ h, float* __restrict__ pstat, int N) {
    int tid  = threadIdx.x;
    int w    = tid >> 6;
    int lane = tid & 63;
    int lc   = lane & 15;    // tile col
    int lq   = lane >> 4;    // quarter
    int rowBase = blockIdx.x * 128 + w * 32;

    f32x4 acc[2][8];
#pragma unroll
    for (int c = 0; c < 8; ++c) {
        float b = bl[c * 16 + lc];
        f32x4 v = {b, b, b, b};
        acc[0][c] = v;
        acc[1][c] = v;
    }

    int r0  = rowBase + lc;
    int r1  = rowBase + 16 + lc;
    int r0c = min(r0, N - 1);
    int r1c = min(r1, N - 1);

    for (int t = 0; t < 8; ++t) {
        bf16x8 a0, a1;
        if (t < 4) {
            int off = t * 32 + lq * 8;
            a0 = *(const bf16x8*)(aggb + (size_t)r0 * D128 + off);
            a1 = *(const bf16x8*)(aggb + (size_t)r1 * D128 + off);
        } else {
            int off = (t - 4) * 32 + lq * 8;
            const float* p0 = x + (size_t)r0c * D128 + off;
            const float* p1 = x + (size_t)r1c * D128 + off;
            float4 u0 = *(const float4*)p0, u1 = *(const float4*)(p0 + 4);
            float4 v0 = *(const float4*)p1, v1 = *(const float4*)(p1 + 4);
            float tu[8] = {u0.x, u0.y, u0.z, u0.w, u1.x, u1.y, u1.z, u1.w};
            float tv[8] = {v0.x, v0.y, v0.z, v0.w, v1.x, v1.y, v1.z, v1.w};
#pragma unroll
            for (int j = 0; j < 8; ++j) {
                a0[j] = (short)f2bf(tu[j]);
                a1[j] = (short)f2bf(tv[j]);
            }
        }
#pragma unroll
        for (int c = 0; c < 8; ++c) {
            bf16x8 bf = *(const bf16x8*)(Bsw + ((size_t)((t * 8 + c) * 64 + lane)) * 8);
            acc[0][c] = __builtin_amdgcn_mfma_f32_16x16x32_bf16(a0, bf, acc[0][c], 0, 0, 0);
            acc[1][c] = __builtin_amdgcn_mfma_f32_16x16x32_bf16(a1, bf, acc[1][c], 0, 0, 0);
        }
    }

    float s[8], ss[8];
#pragma unroll
    for (int c = 0; c < 8; ++c) { s[c] = 0.f; ss[c] = 0.f; }
#pragma unroll
    for (int rh = 0; rh < 2; ++rh) {
#pragma unroll
        for (int reg = 0; reg < 4; ++reg) {
            int row = rowBase + rh * 16 + lq * 4 + reg;   // C-layout row
            if (row < N) {
#pragma unroll
                for (int c = 0; c < 8; ++c) {
                    float v = acc[rh][c][reg];
                    h[(size_t)row * D128 + c * 16 + lc] = v;
                    s[c]  += v;
                    ss[c] += v * v;
                }
            }
        }
    }
#pragma unroll
    for (int c = 0; c < 8; ++c) {
        s[c]  += __shfl_xor(s[c], 16, 64);
        s[c]  += __shfl_xor(s[c], 32, 64);
        ss[c] += __shfl_xor(ss[c], 16, 64);
        ss[c] += __shfl_xor(ss[c], 32, 64);
    }
    if (lq == 0) {
        size_t prow = ((size_t)blockIdx.x * 4 + w) * 256;
#pragma unroll
        for (int c = 0; c < 8; ++c) {
            pstat[prow + c * 16 + lc]       = s[c];
            pstat[prow + 128 + c * 16 + lc] = ss[c];
        }
    }
}

// --- reduce per-wave partial stats -> stats[256] ---------------------------
__global__ __launch_bounds__(256) void statreduce_kernel(
    const float* __restrict__ pstat, float* __restrict__ stats, int NP) {
    int tid = threadIdx.x;
    float loc = 0.f;
    for (int r = blockIdx.x; r < NP; r += gridDim.x)
        loc += pstat[(size_t)r * 256 + tid];
    atomicAdd(&stats[tid], loc);
}

// --- BN params: scale/shift per feature ------------------------------------
__global__ void bnparam_kernel(const float* __restrict__ stats,
                               const float* __restrict__ gamma,
                               const float* __restrict__ beta,
                               float* __restrict__ scl, float* __restrict__ shf,
                               float invN) {
    int d = threadIdx.x;
    float mean = stats[d] * invN;
    float var  = stats[D128 + d] * invN - mean * mean;
    float istd = rsqrtf(var + 1e-5f);
    float sc   = gamma[d] * istd;
    scl[d] = sc;
    shf[d] = beta[d] - mean * sc;
}

// --- finalize: out = relu(h*scale + shift + x), float4, in-place on d_out --
__global__ __launch_bounds__(256) void finalize_kernel(
    const float* __restrict__ h, const float* __restrict__ x,
    const float* __restrict__ scl, const float* __restrict__ shf,
    float* __restrict__ out, long long total4) {
    long long i = (long long)blockIdx.x * 256 + threadIdx.x;
    if (i >= total4) return;
    int d = (int)((i * 4) & 127);
    float4 hv = ((const float4*)h)[i];
    float4 xv = ((const float4*)x)[i];
    float4 sc = *(const float4*)(scl + d);
    float4 sh = *(const float4*)(shf + d);
    float4 o;
    o.x = fmaxf(fmaf(hv.x, sc.x, sh.x) + xv.x, 0.f);
    o.y = fmaxf(fmaf(hv.y, sc.y, sh.y) + xv.y, 0.f);
    o.z = fmaxf(fmaf(hv.z, sc.z, sh.z) + xv.z, 0.f);
    o.w = fmaxf(fmaf(hv.w, sc.w, sh.w) + xv.w, 0.f);
    ((float4*)out)[i] = o;
}

extern "C" void kernel_launch(void* const* d_in, const int* in_sizes, int n_in,
                              void* d_out, int out_size, void* d_ws, size_t ws_size,
                              hipStream_t stream) {
    const float* x     = (const float*)d_in[0];
    const int*   eidx  = (const int*)d_in[1];
    const float* W_l   = (const float*)d_in[2];
    const float* b_l   = (const float*)d_in[3];
    const float* W_r   = (const float*)d_in[4];
    const float* gamma = (const float*)d_in[5];
    const float* beta  = (const float*)d_in[6];

    const int D = in_sizes[3];            // 128
    const int N = in_sizes[0] / D;        // 100000
    const int E = in_sizes[1] / 2;        // 1600000

    const int* src = eidx;
    const int* dst = eidx + E;

    const int NB    = (N + 1023) / 1024;      // node-scan blocks
    const int NBLK  = (N + 127) / 128;        // mfma blocks (782)
    const int Npad  = NBLK * 128;             // padded rows (100096)
    const int NP    = NBLK * 4;               // pstat rows
    const int NBUK  = (N + BSZ2 - 1) / BSZ2;  // buckets (391)
    const int M     = NBUK * SBLK;            // ghist cells (100096)
    const int NB2   = (M + 1023) / 1024;      // ghist-scan blocks
    const int chunk = (E + SBLK - 1) / SBLK;  // edges per sort block (6250)

    // workspace layout (byte cursor, 64B-aligned chunks)
    char* wp = (char*)d_ws;
    auto alloc = [&](size_t bytes) {
        char* p = wp;
        wp += (bytes + 63) & ~(size_t)63;
        return p;
    };
    int*   deg    = (int*)  alloc((size_t)N * 4 + 256 * 4);   // deg + stats
    float* stats  = (float*)(deg + N);
    int*   offs   = (int*)  alloc((size_t)(N + 1) * 4);
    int*   csr    = (int*)  alloc((size_t)E * 4);             // reused as pstat
    int2*  pairs  = (int2*) alloc((size_t)E * 8);
    int*   ghist  = (int*)  alloc((size_t)M * 4);
    int*   gsc    = (int*)  alloc((size_t)(M + 1) * 4);
    int*   bsum   = (int*)  alloc(1024 * 4);                  // shared by both scans
    int*   ebsum  = (int*)  alloc(1024 * 4);
    float* scl    = (float*)alloc(128 * 4);
    float* shf    = (float*)alloc(128 * 4);
    unsigned short* Bsw  = (unsigned short*)alloc(4096 * 16);
    unsigned short* aggb = (unsigned short*)alloc((size_t)Npad * D128 * 2);
    float* pstat = (float*)csr;                               // after gather

    float* h = (float*)d_out;

    // zero deg + stats
    hipMemsetAsync(deg, 0, (size_t)(N + 256) * sizeof(int), stream);

    prep_kernel<<<16, 256, 0, stream>>>(W_l, W_r, Bsw);

    // node-level deg + offs
    hist_kernel<<<(E / 4 + 255) / 256 + 1, 256, 0, stream>>>(dst, deg, E);
    partial_kernel<<<NB, 256, 0, stream>>>(deg, bsum, N);
    scan_bsum_kernel<<<1, 1024, 0, stream>>>(bsum, ebsum, NB, offs + N, E);
    scan_final_kernel<<<NB, 256, 0, stream>>>(deg, ebsum, offs, N);

    // block-private bucket sort: hist -> scan -> scatter
    bhist_kernel<<<SBLK, 256, 0, stream>>>(dst, ghist, E, chunk, NBUK);
    partial_kernel<<<NB2, 256, 0, stream>>>(ghist, bsum, M);
    scan_bsum_kernel<<<1, 1024, 0, stream>>>(bsum, ebsum, NB2, gsc + M, E);
    scan_final_kernel<<<NB2, 256, 0, stream>>>(ghist, ebsum, gsc, M);
    bscatter_kernel<<<SBLK, 256, 0, stream>>>(src, dst, gsc, pairs, E, chunk, NBUK);

    csrbuild_kernel<<<NBUK, 256, 0, stream>>>(pairs, offs, csr, N);

    gather_kernel<<<Npad / 8, 256, 0, stream>>>(offs, csr, x, aggb, N, Npad);

    mfma_kernel<<<NBLK, 256, 0, stream>>>(aggb, x, Bsw, b_l, h, pstat, N);

    statreduce_kernel<<<64, 256, 0, stream>>>(pstat, stats, NP);

    bnparam_kernel<<<1, 128, 0, stream>>>(stats, gamma, beta, scl, shf, 1.0f / (float)N);

    {
        long long total4 = (long long)N * D128 / 4;
        finalize_kernel<<<(int)((total4 + 255) / 256), 256, 0, stream>>>(
            h, x, scl, shf, (float*)d_out, total4);
    }
}

// Round 8
// 306.404 us; speedup vs baseline: 2.4695x; 1.3337x over previous
//
#include <hip/hip_runtime.h>
#include <hip/hip_bf16.h>

// ---------------------------------------------------------------------------
// ResidualSAGEBlock: block-private bucket sort -> CSR(+offs) -> bf16 gather ->
// MFMA bf16 dual GEMM (+fused BN stats) -> BN -> +x -> ReLU.
// N=100000, D=128, E=1600000.
// R2: CSR gather replaced float-atomic scatter: 3095->812us.
// R3: gemm LDS 48->32KB, 5 blocks/CU: 812->761us.
// R4: multi-block scan (was 230us single-CU): 761->546us.
// R5: split gather from GEMM; MFMA bf16 GEMM; fused BN stats: 546->493us.
// R6 FAILED: global-atomic bucket append (cross-XCD line sharing): 493->757us.
// R7: 3-pass block-private counting sort: 757->409us.
// R8: gather from pre-converted bf16 x (halves gather bytes); offs folded into
//     csrbuild (kills hist + first scan chain); packed u32 pairs; mfma reads xb.
// ---------------------------------------------------------------------------

#define D128 128
#define BSH2 8          // log2(nodes per bucket)
#define BSZ2 256        // nodes per bucket
#define MAXBUK 1024     // LDS bound for buckets (NBUK=391 actual)
#define SBLK 256        // sort blocks
#define CAP  5120       // csrbuild LDS capacity (mean 4096, +16 sigma)

typedef short bf16x8 __attribute__((ext_vector_type(8)));
typedef float f32x4  __attribute__((ext_vector_type(4)));

static __device__ __forceinline__ unsigned short f2bf(float f) {
    unsigned u = __builtin_bit_cast(unsigned, f);
    unsigned r = u + 0x7fffu + ((u >> 16) & 1u);   // round-to-nearest-even
    return (unsigned short)(r >> 16);
}
static __device__ __forceinline__ float bflo(unsigned u) {   // low bf16 -> f32
    return __builtin_bit_cast(float, u << 16);
}
static __device__ __forceinline__ float bfhi(unsigned u) {   // high bf16 -> f32
    return __builtin_bit_cast(float, u & 0xffff0000u);
}

// --- build swizzled bf16 B for MFMA ----------------------------------------
// Bsw[t][c][lane][j] = Wcat[t*32 + (lane>>4)*8 + j][c*16 + (lane&15)]
// Wcat[k][d] = k<128 ? Wl[d][k] : Wr[d][k-128].
__global__ __launch_bounds__(256) void prep_kernel(
    const float* __restrict__ Wl, const float* __restrict__ Wr,
    unsigned short* __restrict__ Bsw) {
    int idx = blockIdx.x * 256 + threadIdx.x;   // 0..4095
    if (idx >= 4096) return;
    int l = idx & 63;
    int c = (idx >> 6) & 7;
    int t = idx >> 9;
    int d = c * 16 + (l & 15);
    int kbase = t * 32 + (l >> 4) * 8;
    unsigned short o[8];
#pragma unroll
    for (int j = 0; j < 8; ++j) {
        int k = kbase + j;
        float v = (k < 128) ? Wl[d * 128 + k] : Wr[d * 128 + (k - 128)];
        o[j] = f2bf(v);
    }
    *(uint4*)(Bsw + (size_t)idx * 8) = *(const uint4*)o;
}

// --- sort pass 1: per-block bucket histogram + fused x->bf16 conversion ----
__global__ __launch_bounds__(256) void bhist_kernel(
    const int* __restrict__ dst, int* __restrict__ ghist,
    const float* __restrict__ x, unsigned short* __restrict__ xb,
    int E, int chunk, int NBUK, int total4) {
    __shared__ int lh[MAXBUK];
    int tid = threadIdx.x;
    int b   = blockIdx.x;
    for (int i = tid; i < NBUK; i += 256) lh[i] = 0;
    __syncthreads();
    int beg = b * chunk;
    int end = min(beg + chunk, E);
    for (int i = beg + tid; i < end; i += 256)
        atomicAdd(&lh[dst[i] >> BSH2], 1);
    __syncthreads();
    for (int i = tid; i < NBUK; i += 256) ghist[i * SBLK + b] = lh[i];
    // fused streaming conversion x (fp32) -> xb (bf16)
    for (int i = b * 256 + tid; i < total4; i += 256 * SBLK) {
        float4 v = ((const float4*)x)[i];
        uint2 o;
        o.x = (unsigned)f2bf(v.x) | ((unsigned)f2bf(v.y) << 16);
        o.y = (unsigned)f2bf(v.z) | ((unsigned)f2bf(v.w) << 16);
        ((uint2*)xb)[i] = o;
    }
}

// --- scan stage 1: per-block (1024 elems) partial sums ---------------------
__global__ __launch_bounds__(256) void partial_kernel(const int* __restrict__ deg,
                                                      int* __restrict__ bsum, int N) {
    int tid  = threadIdx.x;
    int base = blockIdx.x * 1024 + tid * 4;
    int s = 0;
    if (base + 3 < N) {
        int4 v = *(const int4*)(deg + base);
        s = v.x + v.y + v.z + v.w;
    } else {
        for (int i = base; i < N; ++i) s += deg[i];
    }
    __shared__ int red[256];
    red[tid] = s;
    __syncthreads();
    for (int off = 128; off > 0; off >>= 1) {
        if (tid < off) red[tid] += red[tid + off];
        __syncthreads();
    }
    if (tid == 0) bsum[blockIdx.x] = red[0];
}

// --- scan stage 2: exclusive scan of block sums (NB <= 1024) ---------------
__global__ __launch_bounds__(1024) void scan_bsum_kernel(
    const int* __restrict__ bsum, int* __restrict__ ebsum,
    int NB, int* __restrict__ outN, int E) {
    __shared__ int buf[2][1024];
    int t = threadIdx.x;
    int v = (t < NB) ? bsum[t] : 0;
    buf[0][t] = v;
    __syncthreads();
    int pi = 0;
    for (int off = 1; off < 1024; off <<= 1) {
        int u = buf[pi][t];
        if (t >= off) u += buf[pi][t - off];
        buf[pi ^ 1][t] = u;
        __syncthreads();
        pi ^= 1;
    }
    if (t < NB) ebsum[t] = buf[pi][t] - v;   // exclusive prefix
    if (t == 0) *outN = E;
}

// --- scan stage 3: per-block exclusive scan + ebsum offset -----------------
__global__ __launch_bounds__(256) void scan_final_kernel(
    const int* __restrict__ deg, const int* __restrict__ ebsum,
    int* __restrict__ offs, int N) {
    int tid  = threadIdx.x;
    int base = blockIdx.x * 1024 + tid * 4;
    int d0 = 0, d1 = 0, d2 = 0, d3 = 0;
    if (base + 3 < N) {
        int4 v = *(const int4*)(deg + base);
        d0 = v.x; d1 = v.y; d2 = v.z; d3 = v.w;
    } else {
        if (base     < N) d0 = deg[base];
        if (base + 1 < N) d1 = deg[base + 1];
        if (base + 2 < N) d2 = deg[base + 2];
        if (base + 3 < N) d3 = deg[base + 3];
    }
    int s = d0 + d1 + d2 + d3;
    __shared__ int buf[2][256];
    buf[0][tid] = s;
    __syncthreads();
    int pi = 0;
    for (int off = 1; off < 256; off <<= 1) {
        int u = buf[pi][tid];
        if (tid >= off) u += buf[pi][tid - off];
        buf[pi ^ 1][tid] = u;
        __syncthreads();
        pi ^= 1;
    }
    int pre = buf[pi][tid] - s + ebsum[blockIdx.x];
    if (base + 3 < N) {
        int4 o = make_int4(pre, pre + d0, pre + d0 + d1, pre + d0 + d1 + d2);
        *(int4*)(offs + base) = o;
    } else {
        int p = pre;
        if (base     < N) { offs[base]     = p; p += d0; }
        if (base + 1 < N) { offs[base + 1] = p; p += d1; }
        if (base + 2 < N) { offs[base + 2] = p; p += d2; }
        if (base + 3 < N) { offs[base + 3] = p; }
    }
}

// --- sort pass 2: scatter packed (src<<8 | dst&255) into private ranges ----
__global__ __launch_bounds__(256) void bscatter_kernel(
    const int* __restrict__ src, const int* __restrict__ dst,
    const int* __restrict__ gsc, unsigned* __restrict__ pairs,
    int E, int chunk, int NBUK) {
    __shared__ int lcur[MAXBUK];
    int tid = threadIdx.x;
    int b   = blockIdx.x;
    for (int i = tid; i < NBUK; i += 256) lcur[i] = gsc[i * SBLK + b];
    __syncthreads();
    int beg = b * chunk;
    int end = min(beg + chunk, E);
    for (int i = beg + tid; i < end; i += 256) {
        int d = dst[i];
        int s = src[i];
        int pos = atomicAdd(&lcur[d >> BSH2], 1);
        pairs[pos] = ((unsigned)s << 8) | (unsigned)(d & 255);
    }
}

// --- per-bucket: local node histogram + scan -> offs; LDS sort -> csr ------
__global__ __launch_bounds__(256) void csrbuild_kernel(
    const unsigned* __restrict__ pairs, const int* __restrict__ gsc,
    int* __restrict__ csr, int* __restrict__ offs, int N, int NBUK, int E) {
    __shared__ int lcnt[BSZ2];
    __shared__ int sbuf[2][BSZ2];
    __shared__ int lcsr[CAP];
    int b   = blockIdx.x;
    int tid = threadIdx.x;
    int nlo = b << BSH2;
    int base = gsc[(size_t)b * SBLK];                       // bucket start
    int end  = (b + 1 < NBUK) ? gsc[(size_t)(b + 1) * SBLK] : E;
    int len  = end - base;
    lcnt[tid] = 0;
    __syncthreads();
    // phase 1: local node histogram
    for (int i = tid; i < len; i += 256)
        atomicAdd(&lcnt[pairs[base + i] & 255u], 1);
    __syncthreads();
    // 256-wide exclusive scan of lcnt
    int c = lcnt[tid];
    sbuf[0][tid] = c;
    __syncthreads();
    int pi = 0;
    for (int off = 1; off < 256; off <<= 1) {
        int u = sbuf[pi][tid];
        if (tid >= off) u += sbuf[pi][tid - off];
        sbuf[pi ^ 1][tid] = u;
        __syncthreads();
        pi ^= 1;
    }
    int pre = sbuf[pi][tid] - c;
    if (nlo + tid <= N) offs[nlo + tid] = base + pre;       // covers offs[N]=E
    lcnt[tid] = pre;                                        // reuse as cursor
    __syncthreads();
    // phase 2: counting sort into LDS, coalesced copy-out
    if (len <= CAP) {
        for (int i = tid; i < len; i += 256) {
            unsigned p = pairs[base + i];
            int pos = atomicAdd(&lcnt[p & 255u], 1);
            lcsr[pos] = (int)(p >> 8);
        }
        __syncthreads();
        for (int i = tid; i < len; i += 256) csr[base + i] = lcsr[i];
    } else {
        // overflow fallback (statistically unreachable)
        for (int i = tid; i < len; i += 256) {
            unsigned p = pairs[base + i];
            int pos = atomicAdd(&lcnt[p & 255u], 1);
            csr[base + pos] = (int)(p >> 8);
        }
    }
}

// --- gather-mean from bf16 xb: aggb[n][:] = mean of xb[src] rows -----------
// 8 nodes/block; 32-lane group per node; half=(lane>>4) processes alternate
// edges; fl=lane&15 owns 8 features (16B uint4 loads).
__global__ __launch_bounds__(256) void gather_kernel(
    const int* __restrict__ offs, const int* __restrict__ csr,
    const unsigned short* __restrict__ xb, unsigned short* __restrict__ aggb,
    int N, int Npad) {
    int tid  = threadIdx.x;
    int l    = tid & 31;
    int half = l >> 4;
    int fl   = l & 15;
    int n    = blockIdx.x * 8 + (tid >> 5);
    if (n >= Npad) return;
    float f[8] = {0.f, 0.f, 0.f, 0.f, 0.f, 0.f, 0.f, 0.f};
    float g[8] = {0.f, 0.f, 0.f, 0.f, 0.f, 0.f, 0.f, 0.f};
    float inv = 0.f;
    if (n < N) {
        int beg = offs[n], end = offs[n + 1];
        int deg = end - beg;
        int k = beg;
        for (; k + 4 <= end; k += 4) {
            int s0 = csr[k + half];
            int s1 = csr[k + 2 + half];
            uint4 v0 = *(const uint4*)(xb + (size_t)s0 * D128 + fl * 8);
            uint4 v1 = *(const uint4*)(xb + (size_t)s1 * D128 + fl * 8);
            f[0] += bflo(v0.x); f[1] += bfhi(v0.x);
            f[2] += bflo(v0.y); f[3] += bfhi(v0.y);
            f[4] += bflo(v0.z); f[5] += bfhi(v0.z);
            f[6] += bflo(v0.w); f[7] += bfhi(v0.w);
            g[0] += bflo(v1.x); g[1] += bfhi(v1.x);
            g[2] += bflo(v1.y); g[3] += bfhi(v1.y);
            g[4] += bflo(v1.z); g[5] += bfhi(v1.z);
            g[6] += bflo(v1.w); g[7] += bfhi(v1.w);
        }
        if (end - k >= 2) {
            int s0 = csr[k + half];
            uint4 v0 = *(const uint4*)(xb + (size_t)s0 * D128 + fl * 8);
            f[0] += bflo(v0.x); f[1] += bfhi(v0.x);
            f[2] += bflo(v0.y); f[3] += bfhi(v0.y);
            f[4] += bflo(v0.z); f[5] += bfhi(v0.z);
            f[6] += bflo(v0.w); f[7] += bfhi(v0.w);
            k += 2;
        }
        if (k < end && half == 0) {
            int s0 = csr[k];
            uint4 v0 = *(const uint4*)(xb + (size_t)s0 * D128 + fl * 8);
            f[0] += bflo(v0.x); f[1] += bfhi(v0.x);
            f[2] += bflo(v0.y); f[3] += bfhi(v0.y);
            f[4] += bflo(v0.z); f[5] += bfhi(v0.z);
            f[6] += bflo(v0.w); f[7] += bfhi(v0.w);
        }
        if (deg > 0) inv = 1.0f / (float)deg;
    }
#pragma unroll
    for (int j = 0; j < 8; ++j) {
        f[j] += g[j];
        f[j] += __shfl_xor(f[j], 16, 64);   // combine halves (stays in group)
    }
    if (half == 0) {
        uint4 o;
        o.x = (unsigned)f2bf(f[0] * inv) | ((unsigned)f2bf(f[1] * inv) << 16);
        o.y = (unsigned)f2bf(f[2] * inv) | ((unsigned)f2bf(f[3] * inv) << 16);
        o.z = (unsigned)f2bf(f[4] * inv) | ((unsigned)f2bf(f[5] * inv) << 16);
        o.w = (unsigned)f2bf(f[6] * inv) | ((unsigned)f2bf(f[7] * inv) << 16);
        *(uint4*)(aggb + (size_t)n * D128 + fl * 8) = o;
    }
}

// --- MFMA dual GEMM + fused BN partial stats -------------------------------
// K=256: ksteps 0-3 read aggb, 4-7 read xb. Per-wave column sums -> pstat.
__global__ __launch_bounds__(256) void mfma_kernel(
    const unsigned short* __restrict__ aggb, const unsigned short* __restrict__ xb,
    const unsigned short* __restrict__ Bsw, const float* __restrict__ bl,
    float* __restrict__ h, float* __restrict__ pstat, int N) {
    int tid  = threadIdx.x;
    int w    = tid >> 6;
    int lane = tid & 63;
    int lc   = lane & 15;    // tile col
    int lq   = lane >> 4;    // quarter
    int rowBase = blockIdx.x * 128 + w * 32;

    f32x4 acc[2][8];
#pragma unroll
    for (int c = 0; c < 8; ++c) {
        float b = bl[c * 16 + lc];
        f32x4 v = {b, b, b, b};
        acc[0][c] = v;
        acc[1][c] = v;
    }

    int r0  = rowBase + lc;
    int r1  = rowBase + 16 + lc;
    int r0c = min(r0, N - 1);
    int r1c = min(r1, N - 1);

    for (int t = 0; t < 8; ++t) {
        const unsigned short* p0;
        const unsigned short* p1;
        if (t < 4) {
            int off = t * 32 + lq * 8;
            p0 = aggb + (size_t)r0 * D128 + off;
            p1 = aggb + (size_t)r1 * D128 + off;
        } else {
            int off = (t - 4) * 32 + lq * 8;
            p0 = xb + (size_t)r0c * D128 + off;
            p1 = xb + (size_t)r1c * D128 + off;
        }
        bf16x8 a0 = *(const bf16x8*)p0;
        bf16x8 a1 = *(const bf16x8*)p1;
#pragma unroll
        for (int c = 0; c < 8; ++c) {
            bf16x8 bf = *(const bf16x8*)(Bsw + ((size_t)((t * 8 + c) * 64 + lane)) * 8);
            acc[0][c] = __builtin_amdgcn_mfma_f32_16x16x32_bf16(a0, bf, acc[0][c], 0, 0, 0);
            acc[1][c] = __builtin_amdgcn_mfma_f32_16x16x32_bf16(a1, bf, acc[1][c], 0, 0, 0);
        }
    }

    float s[8], ss[8];
#pragma unroll
    for (int c = 0; c < 8; ++c) { s[c] = 0.f; ss[c] = 0.f; }
#pragma unroll
    for (int rh = 0; rh < 2; ++rh) {
#pragma unroll
        for (int reg = 0; reg < 4; ++reg) {
            int row = rowBase + rh * 16 + lq * 4 + reg;   // C-layout row
            if (row < N) {
#pragma unroll
                for (int c = 0; c < 8; ++c) {
                    float v = acc[rh][c][reg];
                    h[(size_t)row * D128 + c * 16 + lc] = v;
                    s[c]  += v;
                    ss[c] += v * v;
                }
            }
        }
    }
#pragma unroll
    for (int c = 0; c < 8; ++c) {
        s[c]  += __shfl_xor(s[c], 16, 64);
        s[c]  += __shfl_xor(s[c], 32, 64);
        ss[c] += __shfl_xor(ss[c], 16, 64);
        ss[c] += __shfl_xor(ss[c], 32, 64);
    }
    if (lq == 0) {
        size_t prow = ((size_t)blockIdx.x * 4 + w) * 256;
#pragma unroll
        for (int c = 0; c < 8; ++c) {
            pstat[prow + c * 16 + lc]       = s[c];
            pstat[prow + 128 + c * 16 + lc] = ss[c];
        }
    }
}

// --- reduce per-wave partial stats -> stats[256] ---------------------------
__global__ __launch_bounds__(256) void statreduce_kernel(
    const float* __restrict__ pstat, float* __restrict__ stats, int NP) {
    int tid = threadIdx.x;
    float loc = 0.f;
    for (int r = blockIdx.x; r < NP; r += gridDim.x)
        loc += pstat[(size_t)r * 256 + tid];
    atomicAdd(&stats[tid], loc);
}

// --- BN params: scale/shift per feature ------------------------------------
__global__ void bnparam_kernel(const float* __restrict__ stats,
                               const float* __restrict__ gamma,
                               const float* __restrict__ beta,
                               float* __restrict__ scl, float* __restrict__ shf,
                               float invN) {
    int d = threadIdx.x;
    float mean = stats[d] * invN;
    float var  = stats[D128 + d] * invN - mean * mean;
    float istd = rsqrtf(var + 1e-5f);
    float sc   = gamma[d] * istd;
    scl[d] = sc;
    shf[d] = beta[d] - mean * sc;
}

// --- finalize: out = relu(h*scale + shift + x), float4, in-place on d_out --
__global__ __launch_bounds__(256) void finalize_kernel(
    const float* __restrict__ h, const float* __restrict__ x,
    const float* __restrict__ scl, const float* __restrict__ shf,
    float* __restrict__ out, long long total4) {
    long long i = (long long)blockIdx.x * 256 + threadIdx.x;
    if (i >= total4) return;
    int d = (int)((i * 4) & 127);
    float4 hv = ((const float4*)h)[i];
    float4 xv = ((const float4*)x)[i];
    float4 sc = *(const float4*)(scl + d);
    float4 sh = *(const float4*)(shf + d);
    float4 o;
    o.x = fmaxf(fmaf(hv.x, sc.x, sh.x) + xv.x, 0.f);
    o.y = fmaxf(fmaf(hv.y, sc.y, sh.y) + xv.y, 0.f);
    o.z = fmaxf(fmaf(hv.z, sc.z, sh.z) + xv.z, 0.f);
    o.w = fmaxf(fmaf(hv.w, sc.w, sh.w) + xv.w, 0.f);
    ((float4*)out)[i] = o;
}

extern "C" void kernel_launch(void* const* d_in, const int* in_sizes, int n_in,
                              void* d_out, int out_size, void* d_ws, size_t ws_size,
                              hipStream_t stream) {
    const float* x     = (const float*)d_in[0];
    const int*   eidx  = (const int*)d_in[1];
    const float* W_l   = (const float*)d_in[2];
    const float* b_l   = (const float*)d_in[3];
    const float* W_r   = (const float*)d_in[4];
    const float* gamma = (const float*)d_in[5];
    const float* beta  = (const float*)d_in[6];

    const int D = in_sizes[3];            // 128
    const int N = in_sizes[0] / D;        // 100000
    const int E = in_sizes[1] / 2;        // 1600000

    const int* src = eidx;
    const int* dst = eidx + E;

    const int NBLK  = (N + 127) / 128;        // mfma blocks (782)
    const int Npad  = NBLK * 128;             // padded rows (100096)
    const int NP    = NBLK * 4;               // pstat rows
    const int NBUK  = (N + BSZ2 - 1) / BSZ2;  // buckets (391)
    const int M     = NBUK * SBLK;            // ghist cells (100096)
    const int NB2   = (M + 1023) / 1024;      // ghist-scan blocks
    const int chunk = (E + SBLK - 1) / SBLK;  // edges per sort block (6250)
    const int total4 = N * D128 / 4;          // float4s in x

    // workspace layout (byte cursor, 64B-aligned chunks)
    char* wp = (char*)d_ws;
    auto alloc = [&](size_t bytes) {
        char* p = wp;
        wp += (bytes + 63) & ~(size_t)63;
        return p;
    };
    float*    stats = (float*)   alloc(256 * 4);
    int*      offs  = (int*)     alloc((size_t)(N + 1) * 4);
    int*      csr   = (int*)     alloc((size_t)E * 4);        // reused as pstat
    unsigned* pairs = (unsigned*)alloc((size_t)E * 4);
    int*      ghist = (int*)     alloc((size_t)M * 4);
    int*      gsc   = (int*)     alloc((size_t)(M + 1) * 4);
    int*      bsum  = (int*)     alloc(1024 * 4);
    int*      ebsum = (int*)     alloc(1024 * 4);
    float*    scl   = (float*)   alloc(128 * 4);
    float*    shf   = (float*)   alloc(128 * 4);
    unsigned short* Bsw  = (unsigned short*)alloc(4096 * 16);
    unsigned short* xb   = (unsigned short*)alloc((size_t)N * D128 * 2);
    unsigned short* aggb = (unsigned short*)alloc((size_t)Npad * D128 * 2);
    float* pstat = (float*)csr;                               // after gather

    float* h = (float*)d_out;

    hipMemsetAsync(stats, 0, 256 * sizeof(float), stream);

    prep_kernel<<<16, 256, 0, stream>>>(W_l, W_r, Bsw);

    // bucket hist (+ fused x->bf16) -> scan -> block-private scatter
    bhist_kernel<<<SBLK, 256, 0, stream>>>(dst, ghist, x, xb, E, chunk, NBUK, total4);
    partial_kernel<<<NB2, 256, 0, stream>>>(ghist, bsum, M);
    scan_bsum_kernel<<<1, 1024, 0, stream>>>(bsum, ebsum, NB2, gsc + M, E);
    scan_final_kernel<<<NB2, 256, 0, stream>>>(ghist, ebsum, gsc, M);
    bscatter_kernel<<<SBLK, 256, 0, stream>>>(src, dst, gsc, pairs, E, chunk, NBUK);

    // per-bucket CSR build (also writes offs)
    csrbuild_kernel<<<NBUK, 256, 0, stream>>>(pairs, gsc, csr, offs, N, NBUK, E);

    gather_kernel<<<Npad / 8, 256, 0, stream>>>(offs, csr, xb, aggb, N, Npad);

    mfma_kernel<<<NBLK, 256, 0, stream>>>(aggb, xb, Bsw, b_l, h, pstat, N);

    statreduce_kernel<<<64, 256, 0, stream>>>(pstat, stats, NP);

    bnparam_kernel<<<1, 128, 0, stream>>>(stats, gamma, beta, scl, shf, 1.0f / (float)N);

    {
        long long t4 = (long long)N * D128 / 4;
        finalize_kernel<<<(int)((t4 + 255) / 256), 256, 0, stream>>>(
            h, x, scl, shf, (float*)d_out, t4);
    }
}